// Round 17
// baseline (29.392 us; speedup 1.0000x reference)
//
#include <hip/hip_runtime.h>
#include <hip/hip_fp16.h>

typedef _Float16 f16x8 __attribute__((ext_vector_type(8)));
typedef _Float16 f16x4 __attribute__((ext_vector_type(4)));
typedef _Float16 f16x2 __attribute__((ext_vector_type(2)));
typedef __fp16   fp16v2 __attribute__((ext_vector_type(2)));
typedef float floatx4 __attribute__((ext_vector_type(4)));

#define NEG 0.01f
#define KL_C (-2.8025850929940457f)

// ws layout (float units)
// [0 .. 131071]   W1 f16 MFMA B-fragments: 64 f x 512 uint4 (512 KB)
#define W0HOFF 131072        // 4096 halves
#define B0HOFF 133120        // 4096 halves
#define B1OFF  135168        // 4096 f32
#define W2HOFF 139264        // 4096 halves (f16, pair-interleaved over n)
#define B2OFF  143360        // 64 f32
#define KLPOFF 143424        // 520 f32 partials

__device__ __forceinline__ f16x2 cvt2(float a, float b) {
    union { fp16v2 p; f16x2 h; } u;
    u.p = __builtin_amdgcn_cvt_pkrtz(a, b);
    return u.h;
}

__device__ __forceinline__ float wave_red(float v) {
    v += __shfl_xor(v, 1, 64);  v += __shfl_xor(v, 2, 64);
    v += __shfl_xor(v, 4, 64);  v += __shfl_xor(v, 8, 64);
    v += __shfl_xor(v, 16, 64); v += __shfl_xor(v, 32, 64);
    return v;
}

// prep grid: blocks 0..511 = (feature f = bx>>3, 8-row group g = bx&7):
//   W1 eff (fp32) + KL partial + f16 fragment pack (one (kk,lg) slice).
// blocks 512..519: small tensors eff + KL, d_out = bias init.
__global__ void bayesnam_prep(const float* __restrict__ wmu0, const float* __restrict__ wls0,
                              const float* __restrict__ bmu0, const float* __restrict__ bls0,
                              const float* __restrict__ ew0,  const float* __restrict__ eb0,
                              const float* __restrict__ wmu1, const float* __restrict__ wls1,
                              const float* __restrict__ bmu1, const float* __restrict__ bls1,
                              const float* __restrict__ ew1,  const float* __restrict__ eb1,
                              const float* __restrict__ wmu2, const float* __restrict__ wls2,
                              const float* __restrict__ bmu2, const float* __restrict__ bls2,
                              const float* __restrict__ ew2,  const float* __restrict__ eb2,
                              const float* __restrict__ bias,
                              float* __restrict__ ws, float* __restrict__ out) {
    const int tid = threadIdx.x;
    const int bx  = blockIdx.x;
    __shared__ float red[4];
    if (bx < 512) {
        const int f = bx >> 3;
        const int g = bx & 7;                        // absolute k rows g*8 .. g*8+7
        __shared__ float w1s[8 * 65];
        const size_t base = (size_t)f * 4096 + (size_t)g * 512;
        float klacc = 0.f;
        #pragma unroll
        for (int i = 0; i < 2; ++i) {
            const int idx = i * 256 + tid;           // row*64 + col
            const float m = wmu1[base + idx];
            const float l = wls1[base + idx];
            const float e = ew1[base + idx];
            const float ex = expf(l);
            w1s[(idx >> 6) * 65 + (idx & 63)] = fmaf(ex, e, m);
            klacc += (KL_C - l) + 50.f * fmaf(ex, ex, m * m);
        }
        const float wv = wave_red(klacc * 0.000244140625f);
        if ((tid & 63) == 0) red[tid >> 6] = wv;
        __syncthreads();
        if (tid == 0) ws[KLPOFF + bx] = red[0] + red[1] + red[2] + red[3];
        // fragment pack: this block covers kk = g>>2, lg = g&3 (k = kk*32+lg*8+j)
        if (tid < 64) {
            const int n   = tid >> 4;
            const int l15 = tid & 15;
            const int kk  = g >> 2;
            const int lg  = g & 3;
            const int col = n * 16 + l15;
            union { _Float16 h[8]; uint4 u; } fr;
            #pragma unroll
            for (int j = 0; j < 8; ++j) fr.h[j] = (_Float16)w1s[j * 65 + col];
            ((uint4*)ws)[(size_t)f * 512 + kk * 256 + n * 64 + lg * 16 + l15] = fr.u;
        }
    } else {
        float klacc = 0.f;
        _Float16* w0h = (_Float16*)(ws + W0HOFF);
        _Float16* b0h = (_Float16*)(ws + B0HOFF);
        _Float16* w2h = (_Float16*)(ws + W2HOFF);
        for (int idx = (bx - 512) * 256 + tid; idx < 16448; idx += 2048) {
            const float *mu, *ls, *ew;
            int j, kind; float scale;
            if (idx < 4096)       { j = idx;         mu = wmu0; ls = wls0; ew = ew0; scale = 0.015625f; kind = 0; }
            else if (idx < 8192)  { j = idx - 4096;  mu = bmu0; ls = bls0; ew = eb0; scale = 0.015625f; kind = 1; }
            else if (idx < 12288) { j = idx - 8192;  mu = bmu1; ls = bls1; ew = eb1; scale = 0.015625f; kind = 2; }
            else if (idx < 16384) { j = idx - 12288; mu = wmu2; ls = wls2; ew = ew2; scale = 0.015625f; kind = 3; }
            else                  { j = idx - 16384; mu = bmu2; ls = bls2; ew = eb2; scale = 1.0f;      kind = 4; }
            const float m = mu[j], l = ls[j], e = ew[j];
            const float ex = expf(l);
            const float w  = fmaf(ex, e, m);
            if (kind == 0)      w0h[j] = (_Float16)w;
            else if (kind == 1) b0h[j] = (_Float16)w;
            else if (kind == 2) ws[B1OFF + j] = w;
            else if (kind == 3) {
                // pair-interleave over n: slot = f*64 + (h>>5)*32 + (h&15)*2 + ((h>>4)&1)
                const int h = j & 63;
                w2h[(j & ~63) | ((h >> 5) << 5) | ((h & 15) << 1) | ((h >> 4) & 1)] = (_Float16)w;
            }
            else                ws[B2OFF + j] = w;
            klacc += scale * ((KL_C - l) + 50.f * fmaf(ex, ex, m * m));
        }
        const float bv = bias[0];
        for (int i = (bx - 512) * 256 + tid; i < 16384; i += 2048) out[i] = bv;
        const float wv = wave_red(klacc);
        if ((tid & 63) == 0) red[tid >> 6] = wv;
        __syncthreads();
        if (tid == 0) ws[KLPOFF + 512 + (bx - 512)] = red[0] + red[1] + red[2] + red[3];
    }
}

// Main: per wave 64 rows x 64 hidden (4 row-tiles), 4 features per block.
// R15 structure (empirical optimum of the tile space: R13/R16 bracketed it)
// + s_setprio(1) around the A-build+MFMA cluster (T5: independent waves,
// no barriers in hot loop -> scheduler arbitration regime where it pays).
__global__ __launch_bounds__(256, 3) void bayesnam_main(const float* __restrict__ fin,
                                                        const float* __restrict__ ws,
                                                        float* __restrict__ out) {
    __shared__ uint4 fragLDS[2048];                  // 32 KB: 4 features x 8 KB
    __shared__ __align__(16) float pLDS[644];        // w0,b0 (f16) | b1 (f32) | w2 (f16) | b2
    const int tid = threadIdx.x;
    const int l   = tid & 63;
    const int wid = tid >> 6;
    const int l15 = l & 15;
    const int lg  = l >> 4;
    const int rowbase = blockIdx.x * 256 + wid * 64;
    const int f0 = blockIdx.y * 4;

    // stage fragments: per-lane global src, wave-uniform LDS dest (linear)
    {
        const char* gsrc = (const char*)ws + (size_t)f0 * 8192;
        #pragma unroll
        for (int i = 0; i < 8; ++i) {
            const int chunk = (wid * 8 + i) * 1024;
            __builtin_amdgcn_global_load_lds(
                (const __attribute__((address_space(1))) unsigned int*)(gsrc + chunk + l * 16),
                (__attribute__((address_space(3))) unsigned int*)((char*)fragLDS + chunk),
                16, 0, 0);
        }
    }
    // stage params (2.5 KB for this chunk's 4 features)
    {
        if (tid < 128)      pLDS[tid]       = (ws + W0HOFF + f0 * 32)[tid];
        else                pLDS[tid]       = (ws + B0HOFF + f0 * 32)[tid - 128];
        pLDS[256 + tid] = (ws + B1OFF + f0 * 64)[tid];
        if (tid < 128)      pLDS[512 + tid] = (ws + W2HOFF + f0 * 32)[tid];
        if (tid < 4)        pLDS[640 + tid] = ws[B2OFF + f0 + tid];
    }

    // KL finalize (prep partials ready: same-stream ordering)
    if (blockIdx.x == 0 && blockIdx.y == 0 && tid < 64) {
        float k = 0.f;
        #pragma unroll
        for (int i = 0; i < 9; ++i) {
            const int p = tid + i * 64;
            if (p < 520) k += ws[KLPOFF + p];
        }
        k += __shfl_xor(k, 32, 64); k += __shfl_xor(k, 16, 64); k += __shfl_xor(k, 8, 64);
        k += __shfl_xor(k, 4, 64);  k += __shfl_xor(k, 2, 64);  k += __shfl_xor(k, 1, 64);
        if (tid == 0) out[16384] = k;
    }

    const f16x2 neg2 = {(_Float16)0.01f, (_Float16)0.01f};

    // x for 4 row-tiles, packed to f16 once (8 VGPR instead of 16)
    f16x4 xh[4];
    #pragma unroll
    for (int rt = 0; rt < 4; ++rt) {
        const floatx4 xv = *(const floatx4*)(fin + (size_t)(rowbase + rt * 16 + l15) * 64 + f0);
        xh[rt] = f16x4{(_Float16)xv[0], (_Float16)xv[1], (_Float16)xv[2], (_Float16)xv[3]};
    }

    __syncthreads();                                 // staging complete

    const _Float16* __restrict__ ph = (const _Float16*)pLDS;

    // hoist b2 sum (one value per feature, uniform across lanes)
    const float b2sum = pLDS[640] + pLDS[641] + pLDS[642] + pLDS[643];

    f16x2 ypk[4][4];
    #pragma unroll
    for (int rt = 0; rt < 4; ++rt)
        #pragma unroll
        for (int q = 0; q < 4; ++q) ypk[rt][q] = f16x2{(_Float16)0.f, (_Float16)0.f};

    #pragma unroll 1
    for (int fi = 0; fi < 4; ++fi) {
        floatx4 acc[4][4];
        #pragma unroll
        for (int n = 0; n < 4; ++n) {
            const float bv = pLDS[256 + fi * 64 + n * 16 + l15];
            #pragma unroll
            for (int rt = 0; rt < 4; ++rt) acc[rt][n] = floatx4{bv, bv, bv, bv};
        }

        __builtin_amdgcn_s_setprio(1);
        #pragma unroll
        for (int kk = 0; kk < 2; ++kk) {
            const int kb = kk * 32 + lg * 8;
            union HU { uint4 u; f16x8 v; } wu, bu, bf[4];
            wu.u = *(const uint4*)(ph + fi * 64 + kb);          // w0 (LDS)
            bu.u = *(const uint4*)(ph + 256 + fi * 64 + kb);    // b0 (LDS)
            #pragma unroll
            for (int n = 0; n < 4; ++n) bf[n].u = fragLDS[(fi * 8 + kk * 4 + n) * 64 + l];

            #pragma unroll
            for (int rt = 0; rt < 4; ++rt) {
                const _Float16 xs = xh[rt][fi];
                f16x8 t = wu.v * xs + bu.v;
                f16x8 a = __builtin_elementwise_max(t, t * neg2[0]);
                #pragma unroll
                for (int n = 0; n < 4; ++n)
                    acc[rt][n] = __builtin_amdgcn_mfma_f32_16x16x32_f16(a, bf[n].v, acc[rt][n], 0, 0, 0);
            }
        }
        __builtin_amdgcn_s_setprio(0);

        // packed f16 epilogue: pairs (n0,n1) and (n2,n3); w2 from LDS
        const f16x2 w2p0 = *(const f16x2*)(ph + 1024 + fi * 64 + l15 * 2);
        const f16x2 w2p1 = *(const f16x2*)(ph + 1024 + fi * 64 + 32 + l15 * 2);
        #pragma unroll
        for (int rt = 0; rt < 4; ++rt)
            #pragma unroll
            for (int q = 0; q < 4; ++q) {
                f16x2 h0 = cvt2(acc[rt][0][q], acc[rt][1][q]);
                f16x2 h1 = cvt2(acc[rt][2][q], acc[rt][3][q]);
                f16x2 lk0 = __builtin_elementwise_max(h0, h0 * neg2);
                f16x2 lk1 = __builtin_elementwise_max(h1, h1 * neg2);
                ypk[rt][q] = lk0 * w2p0 + ypk[rt][q];
                ypk[rt][q] = lk1 * w2p1 + ypk[rt][q];
            }
    }

    // unpack + reduce over 16 column-lanes (C layout: col = l&15, row = lg*4+q)
    #pragma unroll
    for (int rt = 0; rt < 4; ++rt)
        #pragma unroll
        for (int q = 0; q < 4; ++q) {
            float v = (float)ypk[rt][q][0] + (float)ypk[rt][q][1];
            v += __shfl_xor(v, 1, 64);
            v += __shfl_xor(v, 2, 64);
            v += __shfl_xor(v, 4, 64);
            v += __shfl_xor(v, 8, 64);
            if (l15 == 0)
                atomicAdd(&out[rowbase + rt * 16 + lg * 4 + q], v + b2sum);
        }
}

extern "C" void kernel_launch(void* const* d_in, const int* in_sizes, int n_in,
                              void* d_out, int out_size, void* d_ws, size_t ws_size,
                              hipStream_t stream) {
    const float* fin  = (const float*)d_in[0];
    const float* wmu0 = (const float*)d_in[1];
    const float* wls0 = (const float*)d_in[2];
    const float* bmu0 = (const float*)d_in[3];
    const float* bls0 = (const float*)d_in[4];
    const float* ew0  = (const float*)d_in[5];
    const float* eb0  = (const float*)d_in[6];
    const float* wmu1 = (const float*)d_in[7];
    const float* wls1 = (const float*)d_in[8];
    const float* bmu1 = (const float*)d_in[9];
    const float* bls1 = (const float*)d_in[10];
    const float* ew1  = (const float*)d_in[11];
    const float* eb1  = (const float*)d_in[12];
    const float* wmu2 = (const float*)d_in[13];
    const float* wls2 = (const float*)d_in[14];
    const float* bmu2 = (const float*)d_in[15];
    const float* bls2 = (const float*)d_in[16];
    const float* ew2  = (const float*)d_in[17];
    const float* eb2  = (const float*)d_in[18];
    const float* bias = (const float*)d_in[19];

    float* ws  = (float*)d_ws;
    float* out = (float*)d_out;

    hipLaunchKernelGGL(bayesnam_prep, dim3(520), dim3(256), 0, stream,
                       wmu0, wls0, bmu0, bls0, ew0, eb0,
                       wmu1, wls1, bmu1, bls1, ew1, eb1,
                       wmu2, wls2, bmu2, bls2, ew2, eb2,
                       bias, ws, out);

    hipLaunchKernelGGL(bayesnam_main, dim3(64, 16), dim3(256), 0, stream,
                       fin, ws, out);
}

// Round 18
// 27.055 us; speedup vs baseline: 1.0863x; 1.0863x over previous
//
#include <hip/hip_runtime.h>
#include <hip/hip_fp16.h>

typedef _Float16 f16x8 __attribute__((ext_vector_type(8)));
typedef _Float16 f16x4 __attribute__((ext_vector_type(4)));
typedef _Float16 f16x2 __attribute__((ext_vector_type(2)));
typedef __fp16   fp16v2 __attribute__((ext_vector_type(2)));
typedef float floatx4 __attribute__((ext_vector_type(4)));

#define NEG 0.01f
#define KL_C (-2.8025850929940457f)

// ws layout (float units)
// [0 .. 131071]   W1 f16 MFMA B-fragments: 64 f x 512 uint4 (512 KB)
#define W0HOFF 131072        // 4096 halves
#define B0HOFF 133120        // 4096 halves
#define B1OFF  135168        // 4096 f32
#define W2HOFF 139264        // 4096 halves (f16, pair-interleaved over n)
#define B2OFF  143360        // 64 f32
#define KLPOFF 143424        // 520 f32 partials

__device__ __forceinline__ f16x2 cvt2(float a, float b) {
    union { fp16v2 p; f16x2 h; } u;
    u.p = __builtin_amdgcn_cvt_pkrtz(a, b);
    return u.h;
}

__device__ __forceinline__ float wave_red(float v) {
    v += __shfl_xor(v, 1, 64);  v += __shfl_xor(v, 2, 64);
    v += __shfl_xor(v, 4, 64);  v += __shfl_xor(v, 8, 64);
    v += __shfl_xor(v, 16, 64); v += __shfl_xor(v, 32, 64);
    return v;
}

// prep grid: blocks 0..511 = (feature f = bx>>3, 8-row group g = bx&7):
//   W1 eff (fp32) + KL partial + f16 fragment pack (one (kk,lg) slice).
// blocks 512..519: small tensors eff + KL, d_out = bias init.
__global__ void bayesnam_prep(const float* __restrict__ wmu0, const float* __restrict__ wls0,
                              const float* __restrict__ bmu0, const float* __restrict__ bls0,
                              const float* __restrict__ ew0,  const float* __restrict__ eb0,
                              const float* __restrict__ wmu1, const float* __restrict__ wls1,
                              const float* __restrict__ bmu1, const float* __restrict__ bls1,
                              const float* __restrict__ ew1,  const float* __restrict__ eb1,
                              const float* __restrict__ wmu2, const float* __restrict__ wls2,
                              const float* __restrict__ bmu2, const float* __restrict__ bls2,
                              const float* __restrict__ ew2,  const float* __restrict__ eb2,
                              const float* __restrict__ bias,
                              float* __restrict__ ws, float* __restrict__ out) {
    const int tid = threadIdx.x;
    const int bx  = blockIdx.x;
    __shared__ float red[4];
    if (bx < 512) {
        const int f = bx >> 3;
        const int g = bx & 7;                        // absolute k rows g*8 .. g*8+7
        __shared__ float w1s[8 * 65];
        const size_t base = (size_t)f * 4096 + (size_t)g * 512;
        float klacc = 0.f;
        #pragma unroll
        for (int i = 0; i < 2; ++i) {
            const int idx = i * 256 + tid;           // row*64 + col
            const float m = wmu1[base + idx];
            const float l = wls1[base + idx];
            const float e = ew1[base + idx];
            const float ex = expf(l);
            w1s[(idx >> 6) * 65 + (idx & 63)] = fmaf(ex, e, m);
            klacc += (KL_C - l) + 50.f * fmaf(ex, ex, m * m);
        }
        const float wv = wave_red(klacc * 0.000244140625f);
        if ((tid & 63) == 0) red[tid >> 6] = wv;
        __syncthreads();
        if (tid == 0) ws[KLPOFF + bx] = red[0] + red[1] + red[2] + red[3];
        // fragment pack: this block covers kk = g>>2, lg = g&3 (k = kk*32+lg*8+j)
        if (tid < 64) {
            const int n   = tid >> 4;
            const int l15 = tid & 15;
            const int kk  = g >> 2;
            const int lg  = g & 3;
            const int col = n * 16 + l15;
            union { _Float16 h[8]; uint4 u; } fr;
            #pragma unroll
            for (int j = 0; j < 8; ++j) fr.h[j] = (_Float16)w1s[j * 65 + col];
            ((uint4*)ws)[(size_t)f * 512 + kk * 256 + n * 64 + lg * 16 + l15] = fr.u;
        }
    } else {
        float klacc = 0.f;
        _Float16* w0h = (_Float16*)(ws + W0HOFF);
        _Float16* b0h = (_Float16*)(ws + B0HOFF);
        _Float16* w2h = (_Float16*)(ws + W2HOFF);
        for (int idx = (bx - 512) * 256 + tid; idx < 16448; idx += 2048) {
            const float *mu, *ls, *ew;
            int j, kind; float scale;
            if (idx < 4096)       { j = idx;         mu = wmu0; ls = wls0; ew = ew0; scale = 0.015625f; kind = 0; }
            else if (idx < 8192)  { j = idx - 4096;  mu = bmu0; ls = bls0; ew = eb0; scale = 0.015625f; kind = 1; }
            else if (idx < 12288) { j = idx - 8192;  mu = bmu1; ls = bls1; ew = eb1; scale = 0.015625f; kind = 2; }
            else if (idx < 16384) { j = idx - 12288; mu = wmu2; ls = wls2; ew = ew2; scale = 0.015625f; kind = 3; }
            else                  { j = idx - 16384; mu = bmu2; ls = bls2; ew = eb2; scale = 1.0f;      kind = 4; }
            const float m = mu[j], l = ls[j], e = ew[j];
            const float ex = expf(l);
            const float w  = fmaf(ex, e, m);
            if (kind == 0)      w0h[j] = (_Float16)w;
            else if (kind == 1) b0h[j] = (_Float16)w;
            else if (kind == 2) ws[B1OFF + j] = w;
            else if (kind == 3) {
                // pair-interleave over n: slot = f*64 + (h>>5)*32 + (h&15)*2 + ((h>>4)&1)
                const int h = j & 63;
                w2h[(j & ~63) | ((h >> 5) << 5) | ((h & 15) << 1) | ((h >> 4) & 1)] = (_Float16)w;
            }
            else                ws[B2OFF + j] = w;
            klacc += scale * ((KL_C - l) + 50.f * fmaf(ex, ex, m * m));
        }
        const float bv = bias[0];
        for (int i = (bx - 512) * 256 + tid; i < 16384; i += 2048) out[i] = bv;
        const float wv = wave_red(klacc);
        if ((tid & 63) == 0) red[tid >> 6] = wv;
        __syncthreads();
        if (tid == 0) ws[KLPOFF + 512 + (bx - 512)] = red[0] + red[1] + red[2] + red[3];
    }
}

// Main: per wave 64 rows x 64 hidden (4 row-tiles), 4 features per block.
// R15 structure — empirical optimum of the tile/occupancy space:
//   16-row (R13) anti-amortizes LDS; 2-feature+n-split (R16) adds overhead;
//   forced VGPR caps (R4/R10/R12) spill; setprio (R17) starves epilogue waves.
// b2 reads hoisted out of the loop (benign R17 component kept).
__global__ __launch_bounds__(256, 3) void bayesnam_main(const float* __restrict__ fin,
                                                        const float* __restrict__ ws,
                                                        float* __restrict__ out) {
    __shared__ uint4 fragLDS[2048];                  // 32 KB: 4 features x 8 KB
    __shared__ __align__(16) float pLDS[644];        // w0,b0 (f16) | b1 (f32) | w2 (f16) | b2
    const int tid = threadIdx.x;
    const int l   = tid & 63;
    const int wid = tid >> 6;
    const int l15 = l & 15;
    const int lg  = l >> 4;
    const int rowbase = blockIdx.x * 256 + wid * 64;
    const int f0 = blockIdx.y * 4;

    // stage fragments: per-lane global src, wave-uniform LDS dest (linear)
    {
        const char* gsrc = (const char*)ws + (size_t)f0 * 8192;
        #pragma unroll
        for (int i = 0; i < 8; ++i) {
            const int chunk = (wid * 8 + i) * 1024;
            __builtin_amdgcn_global_load_lds(
                (const __attribute__((address_space(1))) unsigned int*)(gsrc + chunk + l * 16),
                (__attribute__((address_space(3))) unsigned int*)((char*)fragLDS + chunk),
                16, 0, 0);
        }
    }
    // stage params (2.5 KB for this chunk's 4 features)
    {
        if (tid < 128)      pLDS[tid]       = (ws + W0HOFF + f0 * 32)[tid];
        else                pLDS[tid]       = (ws + B0HOFF + f0 * 32)[tid - 128];
        pLDS[256 + tid] = (ws + B1OFF + f0 * 64)[tid];
        if (tid < 128)      pLDS[512 + tid] = (ws + W2HOFF + f0 * 32)[tid];
        if (tid < 4)        pLDS[640 + tid] = ws[B2OFF + f0 + tid];
    }

    // KL finalize (prep partials ready: same-stream ordering)
    if (blockIdx.x == 0 && blockIdx.y == 0 && tid < 64) {
        float k = 0.f;
        #pragma unroll
        for (int i = 0; i < 9; ++i) {
            const int p = tid + i * 64;
            if (p < 520) k += ws[KLPOFF + p];
        }
        k += __shfl_xor(k, 32, 64); k += __shfl_xor(k, 16, 64); k += __shfl_xor(k, 8, 64);
        k += __shfl_xor(k, 4, 64);  k += __shfl_xor(k, 2, 64);  k += __shfl_xor(k, 1, 64);
        if (tid == 0) out[16384] = k;
    }

    const f16x2 neg2 = {(_Float16)0.01f, (_Float16)0.01f};

    // x for 4 row-tiles, packed to f16 once (8 VGPR instead of 16)
    f16x4 xh[4];
    #pragma unroll
    for (int rt = 0; rt < 4; ++rt) {
        const floatx4 xv = *(const floatx4*)(fin + (size_t)(rowbase + rt * 16 + l15) * 64 + f0);
        xh[rt] = f16x4{(_Float16)xv[0], (_Float16)xv[1], (_Float16)xv[2], (_Float16)xv[3]};
    }

    __syncthreads();                                 // staging complete

    const _Float16* __restrict__ ph = (const _Float16*)pLDS;

    // hoist b2 sum (uniform across lanes; removes 3 LDS reads from the loop)
    const float b2sum = pLDS[640] + pLDS[641] + pLDS[642] + pLDS[643];

    f16x2 ypk[4][4];
    #pragma unroll
    for (int rt = 0; rt < 4; ++rt)
        #pragma unroll
        for (int q = 0; q < 4; ++q) ypk[rt][q] = f16x2{(_Float16)0.f, (_Float16)0.f};

    #pragma unroll 1
    for (int fi = 0; fi < 4; ++fi) {
        floatx4 acc[4][4];
        #pragma unroll
        for (int n = 0; n < 4; ++n) {
            const float bv = pLDS[256 + fi * 64 + n * 16 + l15];
            #pragma unroll
            for (int rt = 0; rt < 4; ++rt) acc[rt][n] = floatx4{bv, bv, bv, bv};
        }

        #pragma unroll
        for (int kk = 0; kk < 2; ++kk) {
            const int kb = kk * 32 + lg * 8;
            union HU { uint4 u; f16x8 v; } wu, bu, bf[4];
            wu.u = *(const uint4*)(ph + fi * 64 + kb);          // w0 (LDS)
            bu.u = *(const uint4*)(ph + 256 + fi * 64 + kb);    // b0 (LDS)
            #pragma unroll
            for (int n = 0; n < 4; ++n) bf[n].u = fragLDS[(fi * 8 + kk * 4 + n) * 64 + l];

            #pragma unroll
            for (int rt = 0; rt < 4; ++rt) {
                const _Float16 xs = xh[rt][fi];
                f16x8 t = wu.v * xs + bu.v;
                f16x8 a = __builtin_elementwise_max(t, t * neg2[0]);
                #pragma unroll
                for (int n = 0; n < 4; ++n)
                    acc[rt][n] = __builtin_amdgcn_mfma_f32_16x16x32_f16(a, bf[n].v, acc[rt][n], 0, 0, 0);
            }
        }

        // packed f16 epilogue: pairs (n0,n1) and (n2,n3); w2 from LDS
        const f16x2 w2p0 = *(const f16x2*)(ph + 1024 + fi * 64 + l15 * 2);
        const f16x2 w2p1 = *(const f16x2*)(ph + 1024 + fi * 64 + 32 + l15 * 2);
        #pragma unroll
        for (int rt = 0; rt < 4; ++rt)
            #pragma unroll
            for (int q = 0; q < 4; ++q) {
                f16x2 h0 = cvt2(acc[rt][0][q], acc[rt][1][q]);
                f16x2 h1 = cvt2(acc[rt][2][q], acc[rt][3][q]);
                f16x2 lk0 = __builtin_elementwise_max(h0, h0 * neg2);
                f16x2 lk1 = __builtin_elementwise_max(h1, h1 * neg2);
                ypk[rt][q] = lk0 * w2p0 + ypk[rt][q];
                ypk[rt][q] = lk1 * w2p1 + ypk[rt][q];
            }
    }

    // unpack + reduce over 16 column-lanes (C layout: col = l&15, row = lg*4+q)
    #pragma unroll
    for (int rt = 0; rt < 4; ++rt)
        #pragma unroll
        for (int q = 0; q < 4; ++q) {
            float v = (float)ypk[rt][q][0] + (float)ypk[rt][q][1];
            v += __shfl_xor(v, 1, 64);
            v += __shfl_xor(v, 2, 64);
            v += __shfl_xor(v, 4, 64);
            v += __shfl_xor(v, 8, 64);
            if (l15 == 0)
                atomicAdd(&out[rowbase + rt * 16 + lg * 4 + q], v + b2sum);
        }
}

extern "C" void kernel_launch(void* const* d_in, const int* in_sizes, int n_in,
                              void* d_out, int out_size, void* d_ws, size_t ws_size,
                              hipStream_t stream) {
    const float* fin  = (const float*)d_in[0];
    const float* wmu0 = (const float*)d_in[1];
    const float* wls0 = (const float*)d_in[2];
    const float* bmu0 = (const float*)d_in[3];
    const float* bls0 = (const float*)d_in[4];
    const float* ew0  = (const float*)d_in[5];
    const float* eb0  = (const float*)d_in[6];
    const float* wmu1 = (const float*)d_in[7];
    const float* wls1 = (const float*)d_in[8];
    const float* bmu1 = (const float*)d_in[9];
    const float* bls1 = (const float*)d_in[10];
    const float* ew1  = (const float*)d_in[11];
    const float* eb1  = (const float*)d_in[12];
    const float* wmu2 = (const float*)d_in[13];
    const float* wls2 = (const float*)d_in[14];
    const float* bmu2 = (const float*)d_in[15];
    const float* bls2 = (const float*)d_in[16];
    const float* ew2  = (const float*)d_in[17];
    const float* eb2  = (const float*)d_in[18];
    const float* bias = (const float*)d_in[19];

    float* ws  = (float*)d_ws;
    float* out = (float*)d_out;

    hipLaunchKernelGGL(bayesnam_prep, dim3(520), dim3(256), 0, stream,
                       wmu0, wls0, bmu0, bls0, ew0, eb0,
                       wmu1, wls1, bmu1, bls1, ew1, eb1,
                       wmu2, wls2, bmu2, bls2, ew2, eb2,
                       bias, ws, out);

    hipLaunchKernelGGL(bayesnam_main, dim3(64, 16), dim3(256), 0, stream,
                       fin, ws, out);
}